// Round 2
// baseline (1927.612 us; speedup 1.0000x reference)
//
#include <hip/hip_runtime.h>

using short8  = __attribute__((ext_vector_type(8))) short;
using floatx4 = __attribute__((ext_vector_type(4))) float;

__device__ inline float b2f(ushort u) {
  union { unsigned u; float f; } x; x.u = ((unsigned)u) << 16; return x.f;
}
__device__ inline ushort f2b(float f) {
  union { float f; unsigned u; } x; x.f = f;
  unsigned r = x.u + 0x7fffu + ((x.u >> 16) & 1u);
  return (ushort)(r >> 16);
}

// ---------- fp32 -> bf16 bulk convert (n4 = n/4 float4s) ----------
__global__ __launch_bounds__(256) void cvt_f32_bf16(
    const float* __restrict__ in, ushort* __restrict__ out, int n4) {
  const int i = blockIdx.x * 256 + threadIdx.x;
  if (i < n4) {
    const float4 v = ((const float4*)in)[i];
    ushort4 o;
    o.x = f2b(v.x); o.y = f2b(v.y); o.z = f2b(v.z); o.w = f2b(v.w);
    ((ushort4*)out)[i] = o;
  }
}

// ---------- transpose+convert: fp32 W[K][*] (row stride ldw, col window 64x64 tiles)
// ----------   -> bf16 Wt[N][K] ----------
__global__ __launch_bounds__(256) void transpose_f32_bf16(
    const float* __restrict__ W, int ldw, ushort* __restrict__ Wt, int K) {
  __shared__ ushort tile[64 * 72];
  const int kb = blockIdx.y * 64, nb = blockIdx.x * 64;
  const int t = threadIdx.x;
  {
    const int tn = t & 63, tk4 = t >> 6;
#pragma unroll
    for (int i = 0; i < 16; ++i) {
      const int k = tk4 + i * 4;
      tile[k * 72 + tn] = f2b(W[(size_t)(kb + k) * ldw + (nb + tn)]);
    }
  }
  __syncthreads();
  {
    const int tk = t & 63, tn4 = t >> 6;
#pragma unroll
    for (int i = 0; i < 16; ++i) {
      const int n = tn4 + i * 4;
      Wt[(size_t)(nb + n) * K + (kb + tk)] = tile[tk * 72 + n];
    }
  }
}

// ---------- C[M][N] = A[M][K] @ Bt[N][K]^T + bias(fp32); A,Bt bf16; out bf16 or fp32 ----------
template <bool F32OUT>
__global__ __launch_bounds__(256) void gemm_bt_bias(
    const ushort* __restrict__ A, const ushort* __restrict__ Bt,
    const float* __restrict__ bias, void* __restrict__ Cout,
    int ldc, int M, int N, int K) {
  __shared__ ushort sA[128 * 72];
  __shared__ ushort sB[128 * 72];
  const int tid = threadIdx.x;
  const int lane = tid & 63, w = tid >> 6;
  const int lm = lane & 15, lq = lane >> 4;
  const int wr = w >> 1, wc = w & 1;
  const int m0 = blockIdx.y * 128, n0 = blockIdx.x * 128;
  floatx4 acc[4][4] = {};
  const int lr = tid >> 3;          // 0..31
  const int lc = (tid & 7) * 8;     // 0..56
  const ushort* Ap = A + (size_t)(m0 + lr) * K + lc;
  const ushort* Bp = Bt + (size_t)(n0 + lr) * K + lc;

  for (int k0 = 0; k0 < K; k0 += 64) {
    int4 av[4], bv[4];
#pragma unroll
    for (int c = 0; c < 4; ++c) {
      av[c] = *(const int4*)(Ap + (size_t)c * 32 * K + k0);
      bv[c] = *(const int4*)(Bp + (size_t)c * 32 * K + k0);
    }
    __syncthreads();
#pragma unroll
    for (int c = 0; c < 4; ++c) {
      *(int4*)&sA[(lr + c * 32) * 72 + lc] = av[c];
      *(int4*)&sB[(lr + c * 32) * 72 + lc] = bv[c];
    }
    __syncthreads();
#pragma unroll
    for (int ks = 0; ks < 2; ++ks) {
      short8 af[4], bf[4];
#pragma unroll
      for (int i = 0; i < 4; ++i)
        af[i] = *(const short8*)&sA[(wr * 64 + i * 16 + lm) * 72 + ks * 32 + lq * 8];
#pragma unroll
      for (int j = 0; j < 4; ++j)
        bf[j] = *(const short8*)&sB[(wc * 64 + j * 16 + lm) * 72 + ks * 32 + lq * 8];
#pragma unroll
      for (int i = 0; i < 4; ++i)
#pragma unroll
        for (int j = 0; j < 4; ++j)
          acc[i][j] = __builtin_amdgcn_mfma_f32_16x16x32_bf16(af[i], bf[j], acc[i][j], 0, 0, 0);
    }
  }
#pragma unroll
  for (int i = 0; i < 4; ++i) {
#pragma unroll
    for (int j = 0; j < 4; ++j) {
      const int row = m0 + wr * 64 + i * 16 + lq * 4;
      const int col = n0 + wc * 64 + j * 16 + lm;
      const float bs = bias[col];
      if (F32OUT) {
        float* C = (float*)Cout;
#pragma unroll
        for (int r = 0; r < 4; ++r)
          C[(size_t)(row + r) * ldc + col] = acc[i][j][r] + bs;
      } else {
        ushort* C = (ushort*)Cout;
#pragma unroll
        for (int r = 0; r < 4; ++r)
          C[(size_t)(row + r) * ldc + col] = f2b(acc[i][j][r] + bs);
      }
    }
  }
}

// ---------- RoPE in-place on q,k halves of qkv bf16 [2048][12288] ----------
__global__ __launch_bounds__(256) void rope_kernel(ushort* __restrict__ qkv) {
  const int s = blockIdx.x;
  const float pos = (float)s;
  for (int i = threadIdx.x; i < 2048; i += 256) {
    const int h = i >> 6, d = i & 63;
    // inv_freq = 10000^(-d/64) = 2^(-d*log2(10000)/64)
    const float inv_freq = exp2f(-(float)d * 0.20762050593045952f);
    const float f = pos * inv_freq;
    float sn, cs; sincosf(f, &sn, &cs);
    const size_t base = (size_t)s * 12288 + h * 128 + d;
    {
      float x1 = b2f(qkv[base]), x2 = b2f(qkv[base + 64]);
      qkv[base]      = f2b(x1 * cs - x2 * sn);
      qkv[base + 64] = f2b(x2 * cs + x1 * sn);
    }
    {
      const size_t kb = base + 4096;
      float x1 = b2f(qkv[kb]), x2 = b2f(qkv[kb + 64]);
      qkv[kb]      = f2b(x1 * cs - x2 * sn);
      qkv[kb + 64] = f2b(x2 * cs + x1 * sn);
    }
  }
}

// ---------- causal flash attention: qkv bf16 -> attn bf16 [2048][4096] ----------
__global__ __launch_bounds__(256) void flash_kernel(
    const ushort* __restrict__ qkv, ushort* __restrict__ attn) {
  constexpr int QKV = 12288;
  __shared__ ushort smem[27136];          // 54272 B
  ushort* sQ  = smem;                     // 128 rows x 136 (aliases K,Vt; dead after preamble)
  ushort* sK  = smem;                     // 64 rows (key) x 136 (d contiguous)
  ushort* sVt = smem + 8704;              // 128 rows (d) x 72 (key contiguous)
  ushort* sP  = smem + 17920;             // 128 rows (q) x 72 (key contiguous)

  const int qt = blockIdx.x, h = blockIdx.y;
  const int q0 = qt * 128;
  const int tid = threadIdx.x;
  const int lane = tid & 63, w = tid >> 6;
  const int lm = lane & 15, lq = lane >> 4;

  // preamble: stage Q tile, pull fragments to registers
  {
    const int r = tid >> 4, d = (tid & 15) * 8;
#pragma unroll
    for (int c = 0; c < 8; ++c) {
      const int rr = r + c * 16;
      *(int4*)&sQ[rr * 136 + d] =
          *(const int4*)(qkv + (size_t)(q0 + rr) * QKV + h * 128 + d);
    }
  }
  __syncthreads();
  short8 aq[2][4];
#pragma unroll
  for (int mt = 0; mt < 2; ++mt)
#pragma unroll
    for (int kk = 0; kk < 4; ++kk)
      aq[mt][kk] = *(const short8*)&sQ[(w * 32 + mt * 16 + lm) * 136 + kk * 32 + lq * 8];

  floatx4 acco[2][8] = {};
  float mrun[2][4], lrun[2][4];
#pragma unroll
  for (int mt = 0; mt < 2; ++mt)
#pragma unroll
    for (int r = 0; r < 4; ++r) { mrun[mt][r] = -1e30f; lrun[mt][r] = 0.f; }

  const int nkv = 2 * (qt + 1);
  const float sc = 0.08838834764831845f * 1.4426950408889634f; // 1/sqrt(128) * log2(e)

  for (int it = 0; it < nkv; ++it) {
    const int kv0 = it * 64;
    int4 kvld[4], vld[4];
    {
      const int r = tid >> 4, d = (tid & 15) * 8;
#pragma unroll
      for (int c = 0; c < 4; ++c) {
        const int rr = r + c * 16;
        kvld[c] = *(const int4*)(qkv + (size_t)(kv0 + rr) * QKV + 4096 + h * 128 + d);
        vld[c]  = *(const int4*)(qkv + (size_t)(kv0 + rr) * QKV + 8192 + h * 128 + d);
      }
    }
    __syncthreads();   // all waves done reading sK/sVt (or sQ) from before
    {
      const int r = tid >> 4, d = (tid & 15) * 8;
#pragma unroll
      for (int c = 0; c < 4; ++c) {
        const int rr = r + c * 16;
        *(int4*)&sK[rr * 136 + d] = kvld[c];
        union { int4 v; ushort u[8]; } uu; uu.v = vld[c];
#pragma unroll
        for (int j = 0; j < 8; ++j) sVt[(d + j) * 72 + rr] = uu.u[j];
      }
    }
    __syncthreads();

    // S = Q K^T  (128q x 64k per block; this wave: 32q)
    floatx4 accs[2][4] = {};
#pragma unroll
    for (int kk = 0; kk < 4; ++kk) {
      short8 bk[4];
#pragma unroll
      for (int nt = 0; nt < 4; ++nt)
        bk[nt] = *(const short8*)&sK[(nt * 16 + lm) * 136 + kk * 32 + lq * 8];
#pragma unroll
      for (int mt = 0; mt < 2; ++mt)
#pragma unroll
        for (int nt = 0; nt < 4; ++nt)
          accs[mt][nt] = __builtin_amdgcn_mfma_f32_16x16x32_bf16(aq[mt][kk], bk[nt], accs[mt][nt], 0, 0, 0);
    }

    // scale + causal mask + tile row-max
    const bool domask = (it >= nkv - 2);
    float tmax[2][4];
#pragma unroll
    for (int mt = 0; mt < 2; ++mt)
#pragma unroll
      for (int r = 0; r < 4; ++r) tmax[mt][r] = -1e30f;
#pragma unroll
    for (int mt = 0; mt < 2; ++mt)
#pragma unroll
      for (int nt = 0; nt < 4; ++nt)
#pragma unroll
        for (int r = 0; r < 4; ++r) {
          float v = accs[mt][nt][r] * sc;
          if (domask) {
            const int qrow = q0 + w * 32 + mt * 16 + lq * 4 + r;
            const int kcol = kv0 + nt * 16 + lm;
            if (kcol > qrow) v = -1e30f;
          }
          accs[mt][nt][r] = v;
          tmax[mt][r] = fmaxf(tmax[mt][r], v);
        }
    // online softmax update
#pragma unroll
    for (int mt = 0; mt < 2; ++mt)
#pragma unroll
      for (int r = 0; r < 4; ++r) {
        float t = tmax[mt][r];
#pragma unroll
        for (int off = 1; off < 16; off <<= 1) t = fmaxf(t, __shfl_xor(t, off, 64));
        const float mnew = fmaxf(mrun[mt][r], t);
        const float alpha = exp2f(mrun[mt][r] - mnew);
        mrun[mt][r] = mnew;
        lrun[mt][r] *= alpha;
#pragma unroll
        for (int nt = 0; nt < 8; ++nt) acco[mt][nt][r] *= alpha;
      }
    // P = exp2(s - m), stash to LDS in A-operand layout (wave-local rows)
    float rsum[2][4] = {};
#pragma unroll
    for (int mt = 0; mt < 2; ++mt)
#pragma unroll
      for (int nt = 0; nt < 4; ++nt)
#pragma unroll
        for (int r = 0; r < 4; ++r) {
          const float p = exp2f(accs[mt][nt][r] - mrun[mt][r]);
          rsum[mt][r] += p;
          sP[(w * 32 + mt * 16 + lq * 4 + r) * 72 + nt * 16 + lm] = f2b(p);
        }
#pragma unroll
    for (int mt = 0; mt < 2; ++mt)
#pragma unroll
      for (int r = 0; r < 4; ++r) {
        float t = rsum[mt][r];
#pragma unroll
        for (int off = 1; off < 16; off <<= 1) t += __shfl_xor(t, off, 64);
        lrun[mt][r] += t;
      }

    // O += P @ V
#pragma unroll
    for (int ks = 0; ks < 2; ++ks) {
      short8 ap[2];
#pragma unroll
      for (int mt = 0; mt < 2; ++mt)
        ap[mt] = *(const short8*)&sP[(w * 32 + mt * 16 + lm) * 72 + ks * 32 + lq * 8];
#pragma unroll
      for (int nt = 0; nt < 8; ++nt) {
        const short8 bv = *(const short8*)&sVt[(nt * 16 + lm) * 72 + ks * 32 + lq * 8];
#pragma unroll
        for (int mt = 0; mt < 2; ++mt)
          acco[mt][nt] = __builtin_amdgcn_mfma_f32_16x16x32_bf16(ap[mt], bv, acco[mt][nt], 0, 0, 0);
      }
    }
  }

  // epilogue: O / l -> attn
#pragma unroll
  for (int mt = 0; mt < 2; ++mt)
#pragma unroll
    for (int r = 0; r < 4; ++r) {
      const float inv = 1.0f / lrun[mt][r];
      const int row = q0 + w * 32 + mt * 16 + lq * 4 + r;
#pragma unroll
      for (int nt = 0; nt < 8; ++nt) {
        const int col = h * 128 + nt * 16 + lm;
        attn[(size_t)row * 4096 + col] = f2b(acco[mt][nt][r] * inv);
      }
    }
}

extern "C" void kernel_launch(void* const* d_in, const int* in_sizes, int n_in,
                              void* d_out, int out_size, void* d_ws, size_t ws_size,
                              hipStream_t stream) {
  // inputs (fp32 per reference): 0=positions(int, unused: positions[b,s]==s),
  // 1=hidden [2048][4096], 2=Wqkv [4096][12288], 3=bqkv [12288],
  // 4=Wo [4096][4096], 5=bo [4096]. Output fp32 [2048][4096].
  const float* hidden = (const float*)d_in[1];
  const float* Wqkv   = (const float*)d_in[2];
  const float* bqkv   = (const float*)d_in[3];
  const float* Wo     = (const float*)d_in[4];
  const float* bo     = (const float*)d_in[5];

  // ws layout (bf16 elements), peak 112 MiB:
  ushort* ws   = (ushort*)d_ws;
  ushort* Wt   = ws;                          // 16,777,216  (32 MiB, reused 4x)
  ushort* hb   = ws + (size_t)16777216;       //  8,388,608  (16 MiB) hidden bf16
  ushort* qkv  = ws + (size_t)25165824;       // 25,165,824  (48 MiB)
  ushort* attn = ws + (size_t)50331648;       //  8,388,608  (16 MiB)

  cvt_f32_bf16<<<8192, 256, 0, stream>>>(hidden, hb, 2097152);

  for (int c = 0; c < 3; ++c) {
    transpose_f32_bf16<<<dim3(64, 64), 256, 0, stream>>>(Wqkv + c * 4096, 12288, Wt, 4096);
    gemm_bt_bias<false><<<dim3(32, 16), 256, 0, stream>>>(
        hb, Wt, bqkv + c * 4096, (void*)(qkv + c * 4096), 12288, 2048, 4096, 4096);
  }

  rope_kernel<<<2048, 256, 0, stream>>>(qkv);
  flash_kernel<<<dim3(16, 32), 256, 0, stream>>>(qkv, attn);

  transpose_f32_bf16<<<dim3(64, 64), 256, 0, stream>>>(Wo, 4096, Wt, 4096);
  gemm_bt_bias<true><<<dim3(32, 16), 256, 0, stream>>>(
      attn, Wt, bo, d_out, 4096, 2048, 4096, 4096);
}

// Round 3
// 1159.021 us; speedup vs baseline: 1.6631x; 1.6631x over previous
//
#include <hip/hip_runtime.h>

using short8  = __attribute__((ext_vector_type(8))) short;
using floatx4 = __attribute__((ext_vector_type(4))) float;

__device__ inline float b2f(ushort u) {
  union { unsigned u; float f; } x; x.u = ((unsigned)u) << 16; return x.f;
}
__device__ inline ushort f2b(float f) {
  union { float f; unsigned u; } x; x.f = f;
  unsigned r = x.u + 0x7fffu + ((x.u >> 16) & 1u);
  return (ushort)(r >> 16);
}

// async global->LDS, 16B per lane; LDS dest = wave-uniform base + lane*16 (m97/m104)
__device__ __forceinline__ void gl_lds16(const void* g, void* l) {
  __builtin_amdgcn_global_load_lds(
      (const __attribute__((address_space(1))) unsigned*)(unsigned long long)g,
      (__attribute__((address_space(3))) unsigned*)(unsigned)(unsigned long long)l,
      16, 0, 0);
}

// ---------- fp32 -> bf16 bulk convert (n4 = n/4 float4s) ----------
__global__ __launch_bounds__(256) void cvt_f32_bf16(
    const float* __restrict__ in, ushort* __restrict__ out, int n4) {
  const int i = blockIdx.x * 256 + threadIdx.x;
  if (i < n4) {
    const float4 v = ((const float4*)in)[i];
    ushort4 o;
    o.x = f2b(v.x); o.y = f2b(v.y); o.z = f2b(v.z); o.w = f2b(v.w);
    ((ushort4*)out)[i] = o;
  }
}

// ---------- transpose+convert: fp32 W[K][*] (stride ldw) -> bf16 Wt[N][K], 64x64 tiles ----------
__global__ __launch_bounds__(256) void transpose_f32_bf16(
    const float* __restrict__ W, int ldw, ushort* __restrict__ Wt, int K) {
  __shared__ ushort tile[64 * 72];
  const int kb = blockIdx.y * 64, nb = blockIdx.x * 64;
  const int t = threadIdx.x;
  {
    const int tn = t & 63, tk4 = t >> 6;
#pragma unroll
    for (int i = 0; i < 16; ++i) {
      const int k = tk4 + i * 4;
      tile[k * 72 + tn] = f2b(W[(size_t)(kb + k) * ldw + (nb + tn)]);
    }
  }
  __syncthreads();
  {
    const int tk = t & 63, tn4 = t >> 6;
#pragma unroll
    for (int i = 0; i < 16; ++i) {
      const int n = tn4 + i * 4;
      Wt[(size_t)(nb + n) * K + (kb + tk)] = tile[tk * 72 + n];
    }
  }
}

// ---------- C[M][N] = A[M][K] @ Bt[N][K]^T + bias(fp32); bf16 in; out bf16 or fp32 ----------
// m97 structure: global_load_lds width-16 staging into unpadded LDS, 2 barriers/K-step.
template <bool F32OUT>
__global__ __launch_bounds__(256) void gemm_bt_bias(
    const ushort* __restrict__ A, const ushort* __restrict__ Bt,
    const float* __restrict__ bias, void* __restrict__ Cout,
    int ldc, int M, int N, int K) {
  __shared__ ushort sA[128 * 64];
  __shared__ ushort sB[128 * 64];
  const int tid = threadIdx.x;
  const int lane = tid & 63, w = tid >> 6;
  const int lm = lane & 15, lq = lane >> 4;
  const int wr = w >> 1, wc = w & 1;
  const int m0 = blockIdx.y * 128, n0 = blockIdx.x * 128;
  floatx4 acc[4][4] = {};

  // staging: wave w covers tile rows [w*32, w*32+32); one instr = 8 rows x 64 cols
  const int srow = w * 32 + (lane >> 3);     // + j*8
  const int scol = (lane & 7) * 8;
  const ushort* Ag = A + (size_t)(m0 + srow) * K + scol;
  const ushort* Bg = Bt + (size_t)(n0 + srow) * K + scol;

  for (int k0 = 0; k0 < K; k0 += 64) {
    __syncthreads();   // previous tile's MFMA reads done before DMA overwrites LDS
#pragma unroll
    for (int j = 0; j < 4; ++j) {
      gl_lds16(Ag + (size_t)j * 8 * K + k0, &sA[(w * 32 + j * 8) * 64]);
      gl_lds16(Bg + (size_t)j * 8 * K + k0, &sB[(w * 32 + j * 8) * 64]);
    }
    __syncthreads();   // drains vmcnt(0): DMA complete for all waves
#pragma unroll
    for (int ks = 0; ks < 2; ++ks) {
      short8 af[4], bf[4];
#pragma unroll
      for (int i = 0; i < 4; ++i)
        af[i] = *(const short8*)&sA[(wr * 64 + i * 16 + lm) * 64 + ks * 32 + lq * 8];
#pragma unroll
      for (int j = 0; j < 4; ++j)
        bf[j] = *(const short8*)&sB[(wc * 64 + j * 16 + lm) * 64 + ks * 32 + lq * 8];
#pragma unroll
      for (int i = 0; i < 4; ++i)
#pragma unroll
        for (int j = 0; j < 4; ++j)
          acc[i][j] = __builtin_amdgcn_mfma_f32_16x16x32_bf16(af[i], bf[j], acc[i][j], 0, 0, 0);
    }
  }
#pragma unroll
  for (int i = 0; i < 4; ++i) {
#pragma unroll
    for (int j = 0; j < 4; ++j) {
      const int row = m0 + wr * 64 + i * 16 + lq * 4;
      const int col = n0 + wc * 64 + j * 16 + lm;
      const float bs = bias[col];
      if (F32OUT) {
        float* C = (float*)Cout;
#pragma unroll
        for (int r = 0; r < 4; ++r)
          C[(size_t)(row + r) * ldc + col] = acc[i][j][r] + bs;
      } else {
        ushort* C = (ushort*)Cout;
#pragma unroll
        for (int r = 0; r < 4; ++r)
          C[(size_t)(row + r) * ldc + col] = f2b(acc[i][j][r] + bs);
      }
    }
  }
}

// ---------- RoPE in-place on q,k halves of qkv bf16 [2048][12288] ----------
__global__ __launch_bounds__(256) void rope_kernel(ushort* __restrict__ qkv) {
  const int s = blockIdx.x;
  const float pos = (float)s;
  for (int i = threadIdx.x; i < 2048; i += 256) {
    const int h = i >> 6, d = i & 63;
    const float inv_freq = exp2f(-(float)d * 0.20762050593045952f); // 10000^(-d/64)
    const float f = pos * inv_freq;
    float sn, cs; sincosf(f, &sn, &cs);
    const size_t base = (size_t)s * 12288 + h * 128 + d;
    {
      float x1 = b2f(qkv[base]), x2 = b2f(qkv[base + 64]);
      qkv[base]      = f2b(x1 * cs - x2 * sn);
      qkv[base + 64] = f2b(x2 * cs + x1 * sn);
    }
    {
      const size_t kb = base + 4096;
      float x1 = b2f(qkv[kb]), x2 = b2f(qkv[kb + 64]);
      qkv[kb]      = f2b(x1 * cs - x2 * sn);
      qkv[kb + 64] = f2b(x2 * cs + x1 * sn);
    }
  }
}

// ---------- causal flash attention v2: 64-row q-tiles, 1024 blocks, longest-first ----------
__global__ __launch_bounds__(256) void flash_kernel(
    const ushort* __restrict__ qkv, ushort* __restrict__ attn) {
  constexpr int QKV = 12288;
  __shared__ ushort smem[22528];          // 45056 B -> 3 blocks/CU
  ushort* sQ  = smem;                     // 64 rows x 136 (aliases sK; dead after preamble)
  ushort* sK  = smem;                     // 64 rows (key) x 136 (d contiguous)
  ushort* sVt = smem + 8704;              // 128 rows (d) x 72 (key contiguous)
  ushort* sP  = smem + 17920;             // 64 rows (q) x 72 (key contiguous)

  const int qt = 31 - blockIdx.x;         // longest blocks (qt=31) dispatch first
  const int h  = blockIdx.y;
  const int q0 = qt * 64;
  const int tid = threadIdx.x;
  const int lane = tid & 63, w = tid >> 6;
  const int lm = lane & 15, lq = lane >> 4;

  // preamble: stage 64x128 Q tile, pull fragments to registers
  {
    const int r = tid >> 4, d = (tid & 15) * 8;
#pragma unroll
    for (int c = 0; c < 4; ++c) {
      const int rr = r + c * 16;
      *(int4*)&sQ[rr * 136 + d] =
          *(const int4*)(qkv + (size_t)(q0 + rr) * QKV + h * 128 + d);
    }
  }
  __syncthreads();
  short8 aq[4];
#pragma unroll
  for (int kk = 0; kk < 4; ++kk)
    aq[kk] = *(const short8*)&sQ[(w * 16 + lm) * 136 + kk * 32 + lq * 8];

  floatx4 acco[8] = {};
  float mrun[4], lrun[4];
#pragma unroll
  for (int r = 0; r < 4; ++r) { mrun[r] = -1e30f; lrun[r] = 0.f; }

  const int nkv = qt + 1;
  const float sc = 0.08838834764831845f * 1.4426950408889634f; // 1/sqrt(128) * log2(e)

  for (int it = 0; it < nkv; ++it) {
    const int kv0 = it * 64;
    int4 kvld[4], vld[4];
    {
      const int r = tid >> 4, d = (tid & 15) * 8;
#pragma unroll
      for (int c = 0; c < 4; ++c) {
        const int rr = r + c * 16;
        kvld[c] = *(const int4*)(qkv + (size_t)(kv0 + rr) * QKV + 4096 + h * 128 + d);
        vld[c]  = *(const int4*)(qkv + (size_t)(kv0 + rr) * QKV + 8192 + h * 128 + d);
      }
    }
    __syncthreads();   // all waves done reading sK/sVt (or sQ preamble)
    {
      const int r = tid >> 4, d = (tid & 15) * 8;
#pragma unroll
      for (int c = 0; c < 4; ++c) {
        const int rr = r + c * 16;
        *(int4*)&sK[rr * 136 + d] = kvld[c];
        union { int4 v; ushort u[8]; } uu; uu.v = vld[c];
#pragma unroll
        for (int j = 0; j < 8; ++j) sVt[(d + j) * 72 + rr] = uu.u[j];
      }
    }
    __syncthreads();

    // S = Q K^T  (64q x 64k per block; this wave: 16q)
    floatx4 accs[4] = {};
#pragma unroll
    for (int kk = 0; kk < 4; ++kk) {
      short8 bk[4];
#pragma unroll
      for (int nt = 0; nt < 4; ++nt)
        bk[nt] = *(const short8*)&sK[(nt * 16 + lm) * 136 + kk * 32 + lq * 8];
#pragma unroll
      for (int nt = 0; nt < 4; ++nt)
        accs[nt] = __builtin_amdgcn_mfma_f32_16x16x32_bf16(aq[kk], bk[nt], accs[nt], 0, 0, 0);
    }

    // scale + causal mask + tile row-max
    const bool domask = (it == nkv - 1);
    float tmax[4];
#pragma unroll
    for (int r = 0; r < 4; ++r) tmax[r] = -1e30f;
#pragma unroll
    for (int nt = 0; nt < 4; ++nt)
#pragma unroll
      for (int r = 0; r < 4; ++r) {
        float v = accs[nt][r] * sc;
        if (domask) {
          const int qrow = q0 + w * 16 + lq * 4 + r;
          const int kcol = kv0 + nt * 16 + lm;
          if (kcol > qrow) v = -1e30f;
        }
        accs[nt][r] = v;
        tmax[r] = fmaxf(tmax[r], v);
      }
    // online softmax update
#pragma unroll
    for (int r = 0; r < 4; ++r) {
      float t = tmax[r];
#pragma unroll
      for (int off = 1; off < 16; off <<= 1) t = fmaxf(t, __shfl_xor(t, off, 64));
      const float mnew = fmaxf(mrun[r], t);
      const float alpha = exp2f(mrun[r] - mnew);
      mrun[r] = mnew;
      lrun[r] *= alpha;
#pragma unroll
      for (int nt = 0; nt < 8; ++nt) acco[nt][r] *= alpha;
    }
    // P = exp2(s - m) -> LDS (wave-private rows)
    float rsum[4] = {};
#pragma unroll
    for (int nt = 0; nt < 4; ++nt)
#pragma unroll
      for (int r = 0; r < 4; ++r) {
        const float p = exp2f(accs[nt][r] - mrun[r]);
        rsum[r] += p;
        sP[(w * 16 + lq * 4 + r) * 72 + nt * 16 + lm] = f2b(p);
      }
#pragma unroll
    for (int r = 0; r < 4; ++r) {
      float t = rsum[r];
#pragma unroll
      for (int off = 1; off < 16; off <<= 1) t += __shfl_xor(t, off, 64);
      lrun[r] += t;
    }

    // O += P @ V
#pragma unroll
    for (int ks = 0; ks < 2; ++ks) {
      const short8 ap = *(const short8*)&sP[(w * 16 + lm) * 72 + ks * 32 + lq * 8];
#pragma unroll
      for (int nt = 0; nt < 8; ++nt) {
        const short8 bv = *(const short8*)&sVt[(nt * 16 + lm) * 72 + ks * 32 + lq * 8];
        acco[nt] = __builtin_amdgcn_mfma_f32_16x16x32_bf16(ap, bv, acco[nt], 0, 0, 0);
      }
    }
  }

  // epilogue: O / l -> attn
#pragma unroll
  for (int r = 0; r < 4; ++r) {
    const float inv = 1.0f / lrun[r];
    const int row = q0 + w * 16 + lq * 4 + r;
#pragma unroll
    for (int nt = 0; nt < 8; ++nt) {
      const int col = h * 128 + nt * 16 + lm;
      attn[(size_t)row * 4096 + col] = f2b(acco[nt][r] * inv);
    }
  }
}

extern "C" void kernel_launch(void* const* d_in, const int* in_sizes, int n_in,
                              void* d_out, int out_size, void* d_ws, size_t ws_size,
                              hipStream_t stream) {
  // inputs (fp32): 0=positions(int, unused), 1=hidden [2048][4096],
  // 2=Wqkv [4096][12288], 3=bqkv [12288], 4=Wo [4096][4096], 5=bo [4096].
  // Output fp32 [2048][4096].
  const float* hidden = (const float*)d_in[1];
  const float* Wqkv   = (const float*)d_in[2];
  const float* bqkv   = (const float*)d_in[3];
  const float* Wo     = (const float*)d_in[4];
  const float* bo     = (const float*)d_in[5];

  // ws layout (bf16 elements), peak 112 MiB:
  ushort* ws   = (ushort*)d_ws;
  ushort* Wt   = ws;                          // 16,777,216  (32 MiB, reused 4x)
  ushort* hb   = ws + (size_t)16777216;       //  8,388,608  (16 MiB) hidden bf16
  ushort* qkv  = ws + (size_t)25165824;       // 25,165,824  (48 MiB)
  ushort* attn = ws + (size_t)50331648;       //  8,388,608  (16 MiB)

  cvt_f32_bf16<<<8192, 256, 0, stream>>>(hidden, hb, 2097152);

  for (int c = 0; c < 3; ++c) {
    transpose_f32_bf16<<<dim3(64, 64), 256, 0, stream>>>(Wqkv + c * 4096, 12288, Wt, 4096);
    gemm_bt_bias<false><<<dim3(32, 16), 256, 0, stream>>>(
        hb, Wt, bqkv + c * 4096, (void*)(qkv + c * 4096), 12288, 2048, 4096, 4096);
  }

  rope_kernel<<<2048, 256, 0, stream>>>(qkv);
  flash_kernel<<<dim3(32, 32), 256, 0, stream>>>(qkv, attn);

  transpose_f32_bf16<<<dim3(64, 64), 256, 0, stream>>>(Wo, 4096, Wt, 4096);
  gemm_bt_bias<true><<<dim3(32, 16), 256, 0, stream>>>(
      attn, Wt, bo, d_out, 4096, 2048, 4096, 4096);
}